// Round 9
// baseline (2108.923 us; speedup 1.0000x reference)
//
#include <hip/hip_runtime.h>
#include <hip/hip_bf16.h>
#include <math.h>

#define NPTS 2048
#define KNB 64
#define SPC (KNB*NPTS)

typedef short bf16x8 __attribute__((ext_vector_type(8)));
typedef float f32x4 __attribute__((ext_vector_type(4)));

static __device__ inline short f2b(float f){ __hip_bfloat16 h = __float2bfloat16(f); short s; __builtin_memcpy(&s,&h,2); return s; }
static __device__ inline float b2f(short s){ __hip_bfloat16 h; __builtin_memcpy(&h,&s,2); return __bfloat162float(h); }

// ---------- weight convert fp32[O][Cs] -> bf16[O][Cd] (zero pad c>=Cs) ----------
__global__ __launch_bounds__(256) void cvt_w(const float* __restrict__ src, short* __restrict__ dst,
                                             int O, int Cs, int Cd)
{
  const int i = blockIdx.x*256 + threadIdx.x;
  if (i >= O*Cd) return;
  const int o = i / Cd, c = i % Cd;
  dst[i] = (c < Cs) ? f2b(src[o*Cs + c]) : (short)0;
}

__global__ __launch_bounds__(256) void fill0(float* __restrict__ p, int n)
{ const int i = blockIdx.x*256 + threadIdx.x; if (i < n) p[i] = 0.f; }

// ---------- ball query, wave-parallel; FEATb[z][k*NPTS+m][8] bf16 ----------
__global__ __launch_bounds__(256) void bq_feat(const float* __restrict__ src,
                                               const float* __restrict__ tgt,
                                               short* __restrict__ featb)
{
  const int z = blockIdx.y;
  const float* xyz = (z < 2) ? src + (size_t)z*NPTS*3 : tgt + (size_t)(z-2)*NPTS*3;
  __shared__ float cs[NPTS*3];
  for (int i = threadIdx.x; i < NPTS*3; i += 256) cs[i] = xyz[i];
  __syncthreads();
  const int wave = threadIdx.x >> 6, lane = threadIdx.x & 63;
  const int m = blockIdx.x*4 + wave;
  short* fb = featb + (long long)z*SPC*8;
  const float px = cs[3*m], py = cs[3*m+1], pz = cs[3*m+2];
  const float sqm = __fadd_rn(__fadd_rn(__fmul_rn(px,px), __fmul_rn(py,py)), __fmul_rn(pz,pz));
  const short pxh = f2b(px), pyh = f2b(py), pzh = f2b(pz);
  int cnt = 0;
  float frx = 0.f, fry = 0.f, frz = 0.f;
  for (int r = 0; r < 32; ++r) {
    const int n = r*64 + lane;
    const float xn = cs[3*n], yn = cs[3*n+1], zn = cs[3*n+2];
    const float sqn = __fadd_rn(__fadd_rn(__fmul_rn(xn,xn), __fmul_rn(yn,yn)), __fmul_rn(zn,zn));
    const float dt  = __fadd_rn(__fadd_rn(__fmul_rn(px,xn), __fmul_rn(py,yn)), __fmul_rn(pz,zn));
    const float d   = __fsub_rn(__fadd_rn(sqm, sqn), __fmul_rn(2.0f, dt));
    const bool hit = (d <= 0.09f);
    const unsigned long long mask = __ballot(hit);
    const int pre = __popcll(mask & ((1ull << lane) - 1ull));
    const int slot = cnt + pre;
    const float rx = xn-px, ry = yn-py, rz = zn-pz;
    if (hit && slot < KNB) {
      short tmp[8] = {pxh, pyh, pzh, f2b(rx), f2b(ry), f2b(rz), 0, 0};
      uint4 raw; __builtin_memcpy(&raw, tmp, 16);
      *(uint4*)&fb[((long long)slot*NPTS + m)*8] = raw;
    }
    if (cnt == 0 && mask) {
      const int fl = __ffsll(mask) - 1;
      frx = __shfl(rx, fl); fry = __shfl(ry, fl); frz = __shfl(rz, fl);
    }
    cnt += __popcll(mask);
    if (cnt >= KNB) break;
  }
  if (cnt < KNB && lane < KNB - cnt) {
    const int slot = cnt + lane;
    short tmp[8] = {pxh, pyh, pzh, f2b(frx), f2b(fry), f2b(frz), 0, 0};
    uint4 raw; __builtin_memcpy(&raw, tmp, 16);
    *(uint4*)&fb[((long long)slot*NPTS + m)*8] = raw;
  }
}

// ---------- fully-fused conv tower, spill-free v2 ----------
// Block owns 16 m. Tile = 64 rows (row = m_local*4 + k_local), 16 iterations of
// 4 k. Each wave owns 16 rows (4 m) end-to-end: no __syncthreads in the loop,
// all LDS traffic wave-private. STAGE 0/1/2 = conv1/conv2/conv3 stats passes;
// stage 2 also maxpools over k in-lane and stores pool[z][m][192].
template<int STAGE>
__global__ __launch_bounds__(256) void convfused(
    const short* __restrict__ featb,
    const short* __restrict__ w1, const short* __restrict__ w2, const short* __restrict__ w3,
    const float* __restrict__ stats1, const float* __restrict__ g1w, const float* __restrict__ g1b,
    const float* __restrict__ stats2, const float* __restrict__ g2w, const float* __restrict__ g2b,
    float* __restrict__ pool,
    float* __restrict__ outPart, long long pZ)
{
  __shared__ __align__(16) short featA[64*40];   // [row][32+pad], cols 8..31 zero
  __shared__ __align__(16) short As[64*136];     // conv1 out (gn1+relu) [row][128+pad]
  __shared__ __align__(16) short C2s[64*264];    // conv2 out (gn2+relu) [row][256+pad]
  const int tid = threadIdx.x;
  const int z = blockIdx.z;
  const int m0 = blockIdx.x * 16;
  const int lane = tid & 63, w = tid >> 6;
  const int l15 = lane & 15, l4 = lane >> 4;
  const short* fz = featb + (long long)z*SPC*8;

  for (int i = tid; i < 64*40/8; i += 256) *(uint4*)&featA[i*8] = make_uint4(0,0,0,0);
  __syncthreads();

  bf16x8 bw1[8];
  #pragma unroll
  for (int tc = 0; tc < 8; ++tc)
    bw1[tc] = *(const bf16x8*)&w1[(tc*16+l15)*32 + l4*8];

  float s1a[4], q1a[4], s2a[8], q2a[8], s3a[6], q3a[6], mx[12];
  #pragma unroll
  for (int j = 0; j < 4; ++j) { s1a[j]=0.f; q1a[j]=0.f; }
  #pragma unroll
  for (int j = 0; j < 8; ++j) { s2a[j]=0.f; q2a[j]=0.f; }
  #pragma unroll
  for (int j = 0; j < 6; ++j) { s3a[j]=0.f; q3a[j]=0.f; }
  #pragma unroll
  for (int j = 0; j < 12; ++j) mx[j] = -1e30f;

  const int bl_m = 4*w + (lane>>2), kl = lane&3;   // staging assignment (lane<16)

  #pragma unroll 1
  for (int it = 0; it < 16; ++it) {
    const int k0 = it*4;
    if (lane < 16) {
      const uint4 v = *(const uint4*)&fz[((long long)(k0+kl)*NPTS + m0 + bl_m)*8];
      *(uint4*)&featA[(bl_m*4 + kl)*40] = v;
    }
    // conv1: 16 rows x 128 ch, K=8 (padded 32)
    const bf16x8 af1 = *(const bf16x8*)&featA[(16*w + l15)*40 + l4*8];
    f32x4 c1[8];
    #pragma unroll
    for (int tc = 0; tc < 8; ++tc)
      c1[tc] = __builtin_amdgcn_mfma_f32_16x16x32_bf16(af1, bw1[tc], (f32x4){0.f,0.f,0.f,0.f}, 0, 0, 0);

    if (STAGE == 0) {
      #pragma unroll
      for (int tc = 0; tc < 8; ++tc)
        #pragma unroll
        for (int r = 0; r < 4; ++r) {
          const float v = c1[tc][r];
          s1a[tc>>1] += v; q1a[tc>>1] = fmaf(v, v, q1a[tc>>1]);
        }
      continue;
    }
    // gn1+relu -> As
    {
      const float* st1 = stats1 + (long long)z*64;
      #pragma unroll
      for (int tc = 0; tc < 8; ++tc) {
        const int c = tc*16 + l15, g = tc>>1;
        const float mu = st1[2*g], rs = st1[2*g+1];
        const float wv = g1w[c], bv = g1b[c];
        #pragma unroll
        for (int r = 0; r < 4; ++r)
          As[(16*w + l4*4 + r)*136 + c] = f2b(fmaxf((c1[tc][r]-mu)*rs*wv + bv, 0.f));
      }
    }
    // conv2: 16 rows x 256 ch, K=128
    f32x4 c2[16];
    #pragma unroll
    for (int j = 0; j < 16; ++j) c2[j] = (f32x4){0.f,0.f,0.f,0.f};
    #pragma unroll
    for (int c0 = 0; c0 < 128; c0 += 32) {
      const bf16x8 af = *(const bf16x8*)&As[(16*w + l15)*136 + c0 + l4*8];
      #pragma unroll
      for (int tc = 0; tc < 16; ++tc) {
        const bf16x8 bw = *(const bf16x8*)&w2[(tc*16+l15)*128 + c0 + l4*8];
        c2[tc] = __builtin_amdgcn_mfma_f32_16x16x32_bf16(af, bw, c2[tc], 0, 0, 0);
      }
    }
    if (STAGE == 1) {
      #pragma unroll
      for (int tc = 0; tc < 16; ++tc)
        #pragma unroll
        for (int r = 0; r < 4; ++r) {
          const float v = c2[tc][r];
          s2a[tc>>1] += v; q2a[tc>>1] = fmaf(v, v, q2a[tc>>1]);
        }
      continue;
    }
    // gn2+relu -> C2s
    {
      const float* st2 = stats2 + (long long)z*64;
      #pragma unroll
      for (int tc = 0; tc < 16; ++tc) {
        const int c = tc*16 + l15, g = tc>>1;
        const float mu = st2[2*g], rs = st2[2*g+1];
        const float wv = g2w[c], bv = g2b[c];
        #pragma unroll
        for (int r = 0; r < 4; ++r)
          C2s[(16*w + l4*4 + r)*264 + c] = f2b(fmaxf((c2[tc][r]-mu)*rs*wv + bv, 0.f));
      }
    }
    // conv3: 16 rows x 192 ch, K=256
    f32x4 c3[12];
    #pragma unroll
    for (int j = 0; j < 12; ++j) c3[j] = (f32x4){0.f,0.f,0.f,0.f};
    #pragma unroll
    for (int c0 = 0; c0 < 256; c0 += 32) {
      const bf16x8 af = *(const bf16x8*)&C2s[(16*w + l15)*264 + c0 + l4*8];
      #pragma unroll
      for (int t6 = 0; t6 < 12; ++t6) {
        const bf16x8 bw = *(const bf16x8*)&w3[(t6*16+l15)*256 + c0 + l4*8];
        c3[t6] = __builtin_amdgcn_mfma_f32_16x16x32_bf16(af, bw, c3[t6], 0, 0, 0);
      }
    }
    // stats + in-lane max over the 4 k's (r indexes k in this row layout)
    #pragma unroll
    for (int t6 = 0; t6 < 12; ++t6) {
      float vm = -1e30f;
      #pragma unroll
      for (int r = 0; r < 4; ++r) {
        const float v = c3[t6][r];
        s3a[t6>>1] += v; q3a[t6>>1] = fmaf(v, v, q3a[t6>>1]);
        vm = fmaxf(vm, v);
      }
      mx[t6] = fmaxf(mx[t6], vm);
    }
  }

  // ---- final reductions ----
  float* pp = outPart + (long long)z*pZ;
  if (STAGE == 0) {
    #pragma unroll
    for (int g = 0; g < 4; ++g) {
      float s = s1a[g], q = q1a[g];
      #pragma unroll
      for (int d = 32; d; d >>= 1) { s += __shfl_down(s, d); q += __shfl_down(q, d); }
      if (lane == 0) { atomicAdd(&pp[2*g], s); atomicAdd(&pp[2*g+1], q); }
    }
  } else if (STAGE == 1) {
    #pragma unroll
    for (int g = 0; g < 8; ++g) {
      float s = s2a[g], q = q2a[g];
      #pragma unroll
      for (int d = 32; d; d >>= 1) { s += __shfl_down(s, d); q += __shfl_down(q, d); }
      if (lane == 0) { atomicAdd(&pp[2*g], s); atomicAdd(&pp[2*g+1], q); }
    }
  } else {
    #pragma unroll
    for (int g = 0; g < 6; ++g) {
      float s = s3a[g], q = q3a[g];
      #pragma unroll
      for (int d = 32; d; d >>= 1) { s += __shfl_down(s, d); q += __shfl_down(q, d); }
      if (lane == 0) { atomicAdd(&pp[2*g], s); atomicAdd(&pp[2*g+1], q); }
    }
    // each lane owns (m = m0+4w+l4, c = t6*16+l15): direct store, no combine
    float* pr = pool + ((long long)z*NPTS + m0 + 4*w + l4)*192;
    #pragma unroll
    for (int t6 = 0; t6 < 12; ++t6) pr[t6*16 + l15] = mx[t6];
  }
}

// ---------- universal MFMA GEMM (tile 128s x 64o) ----------
template<int ABF16>
__global__ __launch_bounds__(256) void mm(
    const void* __restrict__ Ap, long long ldA, long long aZ,
    const float* __restrict__ A2, long long ldA2, long long a2Z,
    const short* __restrict__ Bw, long long bZ,
    void* __restrict__ outp, long long ldo, long long oZ, int outBf16,
    const float* __restrict__ bias,
    const float* __restrict__ rowScale, long long rsZ,
    const float* __restrict__ inStats, long long isZ,
    const float* __restrict__ inW, const float* __restrict__ inB,
    float* __restrict__ outPart, long long pZ, int grpCh,
    int N, int K, int S)
{
  constexpr int RP = 40;
  __shared__ __align__(16) short As[128*RP];
  __shared__ __align__(16) short Bs[64*RP];
  __shared__ float rowS[64], rowQ[64], gSs[4], gQs[4];
  const int tid = threadIdx.x;
  const int z = blockIdx.z;
  const int s_blk = blockIdx.x*128;
  const int o_blk = blockIdx.y*64;
  const int lane = tid & 63;
  const int widx = tid >> 6;
  const int w_s = widx & 1, w_o = widx >> 1;
  const int l15 = lane & 15, l4 = lane >> 4;

  const short* Bz = Bw + (long long)z*bZ;
  const float* stz = inStats ? inStats + (long long)z*isZ : nullptr;

  f32x4 acc[2][4];
  #pragma unroll
  for (int i = 0; i < 2; ++i)
    #pragma unroll
    for (int j = 0; j < 4; ++j) acc[i][j] = (f32x4){0.f,0.f,0.f,0.f};

  if (outPart) {
    if (tid < 64) { rowS[tid] = 0.f; rowQ[tid] = 0.f; }
    if (tid < 4)  { gSs[tid] = 0.f; gQs[tid] = 0.f; }
  }

  for (int c0 = 0; c0 < K; c0 += 32) {
    __syncthreads();
    #pragma unroll
    for (int it = 0; it < 2; ++it) {
      const int ch = tid + it*256;
      const int row = ch >> 2, cq = ch & 3;
      const int gc = c0 + cq*8;
      uint4 raw = make_uint4(0,0,0,0);
      if (gc < K) {
        const long long base = (long long)(s_blk+row)*ldA + gc;
        if (ABF16) {
          raw = *(const uint4*)((const short*)Ap + (long long)z*aZ + base);
          if (stz) {
            short vs[8]; __builtin_memcpy(vs, &raw, 16);
            const int g = gc >> 5;
            const float mu = stz[2*g], rsg = stz[2*g+1];
            short tmp[8];
            #pragma unroll
            for (int j = 0; j < 8; ++j) {
              const float v = (b2f(vs[j]) - mu)*rsg*inW[gc+j] + inB[gc+j];
              tmp[j] = f2b(fmaxf(v, 0.f));
            }
            __builtin_memcpy(&raw, tmp, 16);
          }
        } else {
          const float* Af = (const float*)Ap + (long long)z*aZ + base;
          float4 u0 = *(const float4*)Af;
          float4 u1 = *(const float4*)(Af + 4);
          if (A2) {
            const float* Sf = A2 + (long long)z*a2Z + (long long)(s_blk+row)*ldA2 + gc;
            const float4 s0 = *(const float4*)Sf, s1 = *(const float4*)(Sf + 4);
            u0.x -= s0.x; u0.y -= s0.y; u0.z -= s0.z; u0.w -= s0.w;
            u1.x -= s1.x; u1.y -= s1.y; u1.z -= s1.z; u1.w -= s1.w;
          }
          short tmp[8] = {f2b(u0.x),f2b(u0.y),f2b(u0.z),f2b(u0.w),
                          f2b(u1.x),f2b(u1.y),f2b(u1.z),f2b(u1.w)};
          __builtin_memcpy(&raw, tmp, 16);
        }
      }
      *(uint4*)&As[row*RP + cq*8] = raw;
    }
    {
      const int row = tid >> 2, cq = tid & 3;
      const int gc = c0 + cq*8, go = o_blk + row;
      uint4 raw = make_uint4(0,0,0,0);
      if (go < N && gc < K)
        raw = *(const uint4*)(Bz + (long long)go*K + gc);
      *(uint4*)&Bs[row*RP + cq*8] = raw;
    }
    __syncthreads();
    bf16x8 af[4], bfr[2];
    #pragma unroll
    for (int ts = 0; ts < 4; ++ts)
      af[ts] = *(const bf16x8*)&As[(w_s*64 + ts*16 + l15)*RP + l4*8];
    #pragma unroll
    for (int to = 0; to < 2; ++to)
      bfr[to] = *(const bf16x8*)&Bs[(w_o*32 + to*16 + l15)*RP + l4*8];
    #pragma unroll
    for (int to = 0; to < 2; ++to)
      #pragma unroll
      for (int ts = 0; ts < 4; ++ts)
        acc[to][ts] = __builtin_amdgcn_mfma_f32_16x16x32_bf16(af[ts], bfr[to], acc[to][ts], 0, 0, 0);
  }

  const int s_base = s_blk + w_s*64;
  const int o_base = o_blk + w_o*32;
  float* ozF = (float*)outp + (long long)z*oZ;
  short* ozH = (short*)outp + (long long)z*oZ;
  #pragma unroll
  for (int to = 0; to < 2; ++to) {
    const int o = o_base + to*16 + l15;
    const bool ov = (o < N);
    const float bv = (bias && ov) ? bias[o] : 0.f;
    float ps = 0.f, pq = 0.f;
    #pragma unroll
    for (int ts = 0; ts < 4; ++ts) {
      #pragma unroll
      for (int r = 0; r < 4; ++r) {
        const int s = s_base + ts*16 + l4*4 + r;
        float v = acc[to][ts][r] + bv;
        if (rowScale) v *= rowScale[(long long)z*rsZ + s];
        if (ov) {
          if (outBf16) ozH[(long long)s*ldo + o] = f2b(v);
          else         ozF[(long long)s*ldo + o] = v;
          ps += v; pq = fmaf(v, v, pq);
        }
      }
    }
    if (outPart) {
      ps += __shfl_down(ps, 32); pq += __shfl_down(pq, 32);
      ps += __shfl_down(ps, 16); pq += __shfl_down(pq, 16);
      if (lane < 16) {
        atomicAdd(&rowS[w_o*32 + to*16 + l15], ps);
        atomicAdd(&rowQ[w_o*32 + to*16 + l15], pq);
      }
    }
  }
  if (outPart) {
    __syncthreads();
    if (tid < 64) {
      const int o = o_blk + tid;
      if (o < N) {
        const int gl = o/grpCh - o_blk/grpCh;
        atomicAdd(&gSs[gl], rowS[tid]);
        atomicAdd(&gQs[gl], rowQ[tid]);
      }
    }
    __syncthreads();
    const int g0 = o_blk/grpCh;
    const int hi = (o_blk + 63 < N - 1) ? o_blk + 63 : N - 1;
    if (tid <= hi/grpCh - g0) {
      float* pp = outPart + (long long)z*pZ;
      atomicAdd(&pp[2*(g0+tid)],   gSs[tid]);
      atomicAdd(&pp[2*(g0+tid)+1], gQs[tid]);
    }
  }
}

// ---------- fused QK^T + softmax ----------
__global__ __launch_bounds__(256) void attn_fused(
    const short* __restrict__ qkt,
    short* __restrict__ attb,
    float* __restrict__ colsum)
{
  const int tid = threadIdx.x;
  const int z = blockIdx.y;
  const int n0 = blockIdx.x * 16;
  const int w = tid >> 6, lane = tid & 63;
  const int l15 = lane & 15, l4 = lane >> 4;
  const short* qz = qkt + (long long)z*NPTS*64;
  short* az = attb + (long long)z*NPTS*NPTS;

  const bf16x8 aq0 = *(const bf16x8*)&qz[(n0+l15)*64 + l4*8];
  const bf16x8 aq1 = *(const bf16x8*)&qz[(n0+l15)*64 + 32 + l4*8];

  const int key0 = w * 512;
  float rmax[4], rsum[4], rinv[4];
  #pragma unroll
  for (int r = 0; r < 4; ++r) { rmax[r] = -1e30f; rsum[r] = 0.f; }

  #pragma unroll 1
  for (int t = 0; t < 8; ++t) {
    f32x4 acc[4];
    #pragma unroll
    for (int to = 0; to < 4; ++to) {
      const int k = key0 + t*64 + to*16 + l15;
      const bf16x8 b0 = *(const bf16x8*)&qz[k*64 + l4*8];
      const bf16x8 b1 = *(const bf16x8*)&qz[k*64 + 32 + l4*8];
      f32x4 a = (f32x4){0.f,0.f,0.f,0.f};
      a = __builtin_amdgcn_mfma_f32_16x16x32_bf16(aq0, b0, a, 0, 0, 0);
      a = __builtin_amdgcn_mfma_f32_16x16x32_bf16(aq1, b1, a, 0, 0, 0);
      acc[to] = a;
    }
    #pragma unroll
    for (int r = 0; r < 4; ++r) {
      float tmax = fmaxf(fmaxf(acc[0][r], acc[1][r]), fmaxf(acc[2][r], acc[3][r]));
      tmax = fmaxf(tmax, __shfl_xor(tmax, 1));
      tmax = fmaxf(tmax, __shfl_xor(tmax, 2));
      tmax = fmaxf(tmax, __shfl_xor(tmax, 4));
      tmax = fmaxf(tmax, __shfl_xor(tmax, 8));
      const float mnew = fmaxf(rmax[r], tmax);
      float p = __expf(acc[0][r]-mnew) + __expf(acc[1][r]-mnew)
              + __expf(acc[2][r]-mnew) + __expf(acc[3][r]-mnew);
      p += __shfl_xor(p, 1); p += __shfl_xor(p, 2);
      p += __shfl_xor(p, 4); p += __shfl_xor(p, 8);
      rsum[r] = rsum[r]*__expf(rmax[r]-mnew) + p;
      rmax[r] = mnew;
    }
  }

  __shared__ float sM[4][16], sS[4][16];
  if (l15 == 0) {
    #pragma unroll
    for (int r = 0; r < 4; ++r) { sM[w][l4*4+r] = rmax[r]; sS[w][l4*4+r] = rsum[r]; }
  }
  __syncthreads();
  #pragma unroll
  for (int r = 0; r < 4; ++r) {
    const int row = l4*4 + r;
    const float M = fmaxf(fmaxf(sM[0][row], sM[1][row]), fmaxf(sM[2][row], sM[3][row]));
    const float S = sS[0][row]*__expf(sM[0][row]-M) + sS[1][row]*__expf(sM[1][row]-M)
                  + sS[2][row]*__expf(sM[2][row]-M) + sS[3][row]*__expf(sM[3][row]-M);
    rmax[r] = M;
    rinv[r] = 1.0f / S;
  }

  #pragma unroll 1
  for (int t = 0; t < 8; ++t) {
    #pragma unroll
    for (int to = 0; to < 4; ++to) {
      const int k = key0 + t*64 + to*16 + l15;
      const bf16x8 b0 = *(const bf16x8*)&qz[k*64 + l4*8];
      const bf16x8 b1 = *(const bf16x8*)&qz[k*64 + 32 + l4*8];
      f32x4 a = (f32x4){0.f,0.f,0.f,0.f};
      a = __builtin_amdgcn_mfma_f32_16x16x32_bf16(aq0, b0, a, 0, 0, 0);
      a = __builtin_amdgcn_mfma_f32_16x16x32_bf16(aq1, b1, a, 0, 0, 0);
      short v4[4]; float cs = 0.f;
      #pragma unroll
      for (int r = 0; r < 4; ++r) {
        const float v = __expf(a[r] - rmax[r]) * rinv[r];
        v4[r] = f2b(v); cs += v;
      }
      uint2 raw; __builtin_memcpy(&raw, v4, 8);
      *(uint2*)&az[(long long)k*NPTS + n0 + l4*4] = raw;
      cs += __shfl_xor(cs, 16);
      cs += __shfl_xor(cs, 32);
      if (l4 == 0) atomicAdd(&colsum[(long long)z*NPTS + k], cs);
    }
  }
}

// ---------- finalize GN stats ----------
__global__ void fin_stats(float* __restrict__ part, float* __restrict__ stats,
                          long long slotStride, int G, float invGS)
{
  const int g = threadIdx.x;
  float* p  = part  + (long long)blockIdx.x * slotStride;
  float* st = stats + (long long)blockIdx.x * slotStride;
  if (g < G) {
    const float mu  = p[2*g] * invGS;
    const float var = p[2*g+1] * invGS - mu*mu;
    st[2*g]   = mu;
    st[2*g+1] = rsqrtf(var + 1e-5f);
    p[2*g] = 0.f; p[2*g+1] = 0.f;
  }
}

// ---------- gn+relu on POOLt [4][NPTS][192] ----------
__global__ __launch_bounds__(256) void gn_pool(float* __restrict__ pool,
    const float* __restrict__ stats, const float* __restrict__ w, const float* __restrict__ b)
{
  const int i = blockIdx.x*256 + threadIdx.x;
  const int z = i / (NPTS*192);
  const int c = i % 192;
  const int g = c >> 5;
  const float* st = stats + z*64;
  const float v = (pool[i] - st[2*g]) * st[2*g+1] * w[c] + b[c];
  pool[i] = fmaxf(v, 0.f);
}

// ---------- FEATS slot[n][c] = xin[n][c] + relu(gn(t[n][c])) ----------
__global__ __launch_bounds__(256) void gn_resid(const float* __restrict__ t,
    const float* __restrict__ xin, long long xZ, long long xld,
    const float* __restrict__ stats,
    const float* __restrict__ w, const float* __restrict__ b,
    float* __restrict__ outp, long long oZ)
{
  const int i = blockIdx.x*256 + threadIdx.x;
  const int z = blockIdx.y;
  const int n = i / 192, c = i % 192, g = c >> 5;
  const float* st = stats + z*16;
  const float v = (t[(long long)z*NPTS*192 + i] - st[2*g]) * st[2*g+1] * w[c] + b[c];
  outp[(long long)z*oZ + (long long)n*768 + c] =
      xin[(long long)z*xZ + (long long)n*xld + c] + fmaxf(v, 0.f);
}

// ---------- transpose -> bf16: src[z][R][C] -> dst[z][C][R] ----------
template<int SRCF32>
__global__ __launch_bounds__(256) void tr2bf(const void* __restrict__ src, short* __restrict__ dst,
                                             long long sZ, long long dZ, int R, int C)
{
  __shared__ float t[32][33];
  const int z = blockIdx.z;
  const int c0 = blockIdx.x*32, r0 = blockIdx.y*32;
  const int tx = threadIdx.x % 32, ty = threadIdx.x / 32;
  #pragma unroll
  for (int j = 0; j < 4; ++j) {
    const int r = r0 + ty + j*8;
    const long long idx = (long long)z*sZ + (long long)r*C + c0 + tx;
    t[ty + j*8][tx] = SRCF32 ? ((const float*)src)[idx] : b2f(((const short*)src)[idx]);
  }
  __syncthreads();
  #pragma unroll
  for (int j = 0; j < 4; ++j) {
    const int c = c0 + ty + j*8;
    dst[(long long)z*dZ + (long long)c*R + r0 + tx] = f2b(t[tx][ty + j*8]);
  }
}

// 1/(1e-9+s) -> o; zero s for next use
__global__ __launch_bounds__(256) void recip_zero(float* __restrict__ s, float* __restrict__ o, int n)
{ const int i = blockIdx.x*256 + threadIdx.x; if (i < n) { o[i] = 1.0f/(1e-9f + s[i]); s[i] = 0.f; } }

// ---------- fuse epilogue: GN(16x48) + leaky(0.2) + L2 norm ----------
__global__ __launch_bounds__(256) void finalize_gn(const float* __restrict__ fused,
    const float* __restrict__ stats, const float* __restrict__ w, const float* __restrict__ b,
    float* __restrict__ outp, long long oZ)
{
  const int n = blockIdx.x, z = blockIdx.y, tid = threadIdx.x;
  const float* fz = fused + ((long long)z*NPTS + n)*768;
  const float* st = stats + z*32;
  __shared__ float vbuf[768];
  __shared__ float red[256];
  float ss = 0.f;
  for (int c = tid; c < 768; c += 256) {
    float v = fz[c];
    const int g = c / 48;
    v = (v - st[2*g]) * st[2*g+1] * w[c] + b[c];
    v = v > 0.f ? v : 0.2f * v;
    vbuf[c] = v;
    ss = fmaf(v, v, ss);
  }
  red[tid] = ss; __syncthreads();
  for (int st_ = 128; st_; st_ >>= 1) { if (tid < st_) red[tid] += red[tid+st_]; __syncthreads(); }
  const float inv = 1.0f / (sqrtf(red[0]) + 1e-8f);
  float* ob = outp + (long long)z*oZ + (long long)n*768;
  for (int c = tid; c < 768; c += 256) ob[c] = vbuf[c] * inv;
}

extern "C" void kernel_launch(void* const* d_in, const int* in_sizes, int n_in,
                              void* d_out, int out_size, void* d_ws, size_t ws_size,
                              hipStream_t stream)
{
  const float* src = (const float*)d_in[0];
  const float* tgt = (const float*)d_in[1];
  const float* lfw[3]  = {(const float*)d_in[5], (const float*)d_in[8],  (const float*)d_in[11]};
  const float* lfgw[3] = {(const float*)d_in[6], (const float*)d_in[9],  (const float*)d_in[12]};
  const float* lfgb[3] = {(const float*)d_in[7], (const float*)d_in[10], (const float*)d_in[13]};
  const float* qk_w = (const float*)d_in[14];
  const float* v_w  = (const float*)d_in[15];
  const float* v_b  = (const float*)d_in[16];
  const float* t_w  = (const float*)d_in[17];
  const float* t_b  = (const float*)d_in[18];
  const float* bgw  = (const float*)d_in[19];
  const float* bgb  = (const float*)d_in[20];
  const float* fw   = (const float*)d_in[21];
  const float* fgw  = (const float*)d_in[22];
  const float* fgb  = (const float*)d_in[23];
  float* dout = (float*)d_out;

  const size_t availFl = ws_size / sizeof(float);
  float* ws = (float*)d_ws;
  size_t off = 0;
  float* POOLt = ws + off; off += (size_t)4*NPTS*192;     // [4][n][192]
  float* PART  = ws + off; off += 1024;
  float* STATS = ws + off; off += 1024;
  float* SB    = ws + off; off += (size_t)4*NPTS;
  float* SINV  = ws + off; off += (size_t)4*NPTS;
  // bf16 weights (lfw0b padded to K=32; qkwb padded to 64 rows/head)
  short* wreg = (short*)(ws + off);
  short* lfw0b = wreg;              // 128x32
  short* lfw1b = lfw0b + 4096;      // 256x128
  short* lfw2b = lfw1b + 32768;     // 192x256
  short* qkwb  = lfw2b + 49152;     // 4x64x192 (padded)
  short* vwb   = qkwb + 49152;      // 4x192x192
  short* twb   = vwb + 147456;      // 4x192x192
  short* fwb   = twb + 147456;      // 768x768
  off += (4096+32768+49152+49152+147456+147456+589824 + 1)/2 + 8;
  short* FEATb = (short*)(ws + off); off += (size_t)4*SPC*8/2;  // [4][k*NPTS+m][8]
  off = (off + 63) & ~(size_t)63;
  float* REG = ws + off;
  const size_t regAvail = (availFl > off) ? (availFl - off) : 0;

  // attention batching: XRt+Tt+FUSED + (QKT[.][64]+Vt+Vc)/2 + ATTB/2 per z
  const size_t perZ = 4915200;
  int nz;
  if      (regAvail >= 4*perZ) nz = 4;
  else if (regAvail >= 2*perZ) nz = 2;
  else if (regAvail >= perZ)   nz = 1;
  else return;

  // attn view of REG
  float* XRt   = REG;                               // [nz][n][192]
  float* Tt    = XRt + (size_t)nz*NPTS*192;         // [nz][n][192]
  float* FUSED = Tt  + (size_t)nz*NPTS*192;         // [nz][n][768]
  short* QKT   = (short*)(FUSED + (size_t)nz*NPTS*768);  // [nz][n][64]
  short* Vt    = QKT + (size_t)nz*NPTS*64;          // [nz][n][192]
  short* Vc    = Vt  + (size_t)nz*NPTS*192;         // [nz][192][n]
  short* ATTB  = Vc  + (size_t)nz*NPTS*192;         // [nz][m][n]

  dim3 b256(256);
  const float invConv = 1.0f / (32.0f * (float)SPC);

  cvt_w<<<dim3(16),  b256, 0, stream>>>(lfw[0], lfw0b, 128, 6, 32);
  cvt_w<<<dim3(128), b256, 0, stream>>>(lfw[1], lfw1b, 256, 128, 128);
  cvt_w<<<dim3(192), b256, 0, stream>>>(lfw[2], lfw2b, 192, 256, 256);
  fill0<<<dim3(96), b256, 0, stream>>>((float*)qkwb, 24576);   // zero the padded qk weights
  for (int i = 0; i < 4; ++i)
    cvt_w<<<dim3(36), b256, 0, stream>>>(qk_w + (size_t)i*48*192, qkwb + (size_t)i*64*192, 48, 192, 192);
  cvt_w<<<dim3(576), b256, 0, stream>>>(v_w,  vwb,  768, 192, 192);
  cvt_w<<<dim3(576), b256, 0, stream>>>(t_w,  twb,  768, 192, 192);
  cvt_w<<<dim3(2304),b256, 0, stream>>>(fw,   fwb,  768, 768, 768);
  fill0<<<dim3(4), b256, 0, stream>>>(PART, 1024);
  fill0<<<dim3(32), b256, 0, stream>>>(SB, 4*NPTS);

  // ---- ball query ----
  bq_feat<<<dim3(NPTS/4, 4), b256, 0, stream>>>(src, tgt, FEATb);

  // ---- fused conv tower: 3 stats passes, no HBM intermediates, no spills ----
  convfused<0><<<dim3(128, 1, 4), b256, 0, stream>>>(
      FEATb, lfw0b, nullptr, nullptr,
      nullptr, nullptr, nullptr, nullptr, nullptr, nullptr,
      nullptr, PART, 64);
  fin_stats<<<4, 32, 0, stream>>>(PART, STATS, 64, 4, invConv);
  convfused<1><<<dim3(128, 1, 4), b256, 0, stream>>>(
      FEATb, lfw0b, lfw1b, nullptr,
      STATS, lfgw[0], lfgb[0], nullptr, nullptr, nullptr,
      nullptr, PART+256, 64);
  fin_stats<<<4, 32, 0, stream>>>(PART+256, STATS+256, 64, 8, invConv);
  convfused<2><<<dim3(128, 1, 4), b256, 0, stream>>>(
      FEATb, lfw0b, lfw1b, lfw2b,
      STATS, lfgw[0], lfgb[0], STATS+256, lfgw[1], lfgb[1],
      POOLt, PART+512, 64);
  fin_stats<<<4, 32, 0, stream>>>(PART+512, STATS+512, 64, 6, invConv);
  gn_pool<<<dim3(4*NPTS*192/256), b256, 0, stream>>>(POOLt, STATS+512, lfgw[2], lfgb[2]);

  // ---- attention + fuse, nz clouds per batch ----
  for (int bb0 = 0; bb0 < 4; bb0 += nz) {
    for (int i = 0; i < 4; ++i) {
      const float* Xin; long long xZ, xld;
      if (i == 0) { Xin = POOLt + (size_t)bb0*NPTS*192; xZ = (long long)NPTS*192; xld = 192; }
      else        { Xin = dout + (size_t)bb0*NPTS*768 + (size_t)(i-1)*192; xZ = (long long)NPTS*768; xld = 768; }
      // qk -> QKT [n][64] bf16 (cols 48..63 zero via padded weights)
      mm<0><<<dim3(16, 1, nz), b256, 0, stream>>>(
          Xin, xld, xZ, nullptr,0,0,
          qkwb + (size_t)i*64*192, 0, QKT, 64, (long long)NPTS*64, 1,
          nullptr, nullptr,0, nullptr,0,nullptr,nullptr,
          nullptr, 0, 1, 64, 192, NPTS);
      // v -> Vt [n][192] bf16 (+bias)
      mm<0><<<dim3(16, 3, nz), b256, 0, stream>>>(
          Xin, xld, xZ, nullptr,0,0,
          vwb + (size_t)i*192*192, 0, Vt, 192, (long long)NPTS*192, 1,
          v_b + (size_t)i*192, nullptr,0, nullptr,0,nullptr,nullptr,
          nullptr, 0, 1, 192, 192, NPTS);
      // fused QK^T + softmax -> ATTB bf16 [m][n] + column sums into SB
      attn_fused<<<dim3(NPTS/16, nz), b256, 0, stream>>>(QKT, ATTB, SB);
      recip_zero<<<dim3(nz*NPTS/256), b256, 0, stream>>>(SB, SINV, nz*NPTS);
      tr2bf<0><<<dim3(6, 64, nz), b256, 0, stream>>>(Vt, Vc,
          (long long)NPTS*192, (long long)192*NPTS, NPTS, 192);
      // x_r^T [m][192] = (ATTB . Vc^T) * sinv[m]
      mm<1><<<dim3(16, 3, nz), b256, 0, stream>>>(
          ATTB, NPTS, (long long)NPTS*NPTS, nullptr,0,0,
          Vc, (long long)192*NPTS, XRt, 192, (long long)NPTS*192, 0,
          nullptr, SINV, NPTS, nullptr,0,nullptr,nullptr,
          nullptr, 0, 1, 192, NPTS, NPTS);
      // t [n][192] = (x - x_r) . t_w^T + t_b, + stats
      mm<0><<<dim3(16, 3, nz), b256, 0, stream>>>(
          Xin, xld, xZ, XRt, 192, (long long)NPTS*192,
          twb + (size_t)i*192*192, 0, Tt, 192, (long long)NPTS*192, 0,
          t_b + (size_t)i*192, nullptr,0, nullptr,0,nullptr,nullptr,
          PART+768, 16, 32, 192, 192, NPTS);
      fin_stats<<<nz, 32, 0, stream>>>(PART+768, STATS+768, 16, 6, 1.0f/65536.0f);
      gn_resid<<<dim3(NPTS*192/256, nz), b256, 0, stream>>>(
          Tt, Xin, xZ, xld, STATS+768,
          bgw + (size_t)i*192, bgb + (size_t)i*192,
          dout + (size_t)bb0*NPTS*768 + (size_t)i*192, (long long)NPTS*768);
    }
    // fuse
    mm<0><<<dim3(16, 12, nz), b256, 0, stream>>>(
        dout + (size_t)bb0*NPTS*768, 768, (long long)NPTS*768, nullptr,0,0,
        fwb, 0, FUSED, 768, (long long)NPTS*768, 0,
        nullptr, nullptr,0, nullptr,0,nullptr,nullptr,
        PART+832, 32, 48, 768, 768, NPTS);
    fin_stats<<<nz, 32, 0, stream>>>(PART+832, STATS+832, 32, 16, 1.0f/98304.0f);
    finalize_gn<<<dim3(NPTS, nz), b256, 0, stream>>>(
        FUSED, STATS+832, fgw, fgb,
        dout + (size_t)bb0*NPTS*768, (long long)NPTS*768);
  }
}